// Round 1
// 16482.048 us; speedup vs baseline: 2.1014x; 2.1014x over previous
//
#include <hip/hip_runtime.h>
#include <stdint.h>

// ============================================================================
// RNN2Layer: proj GEMM -> persistent Euler-scan kernel -> output GEMM
// All fp32. This round: replace per-step device-scope fences (which compile
// to buffer_wbl2/buffer_inv = full-L2 writeback/invalidate on gfx950's
// non-coherent per-XCD L2s; rocprof showed 8.65 GB WRITE_SIZE = 32x write
// amplification) with fence-free SYSTEM-scope relaxed atomics for ALL
// cross-WG data (h stores, h staging loads, flags). sc0+sc1 accesses bypass
// L1 and L2 and are coherent at the memory-side Infinity Cache, so no cache
// maintenance instructions are needed on the per-step critical path.
//
// Layout of d_out:  [0 .. 16777216)               output  [1024][64][256]
//                   [16777216 .. 16777216+67108864) embeddings [1024][64][1024]
// The embeddings region initially holds proj (= input @ W_in); the scan
// overwrites emb[t] with h_t after consuming u_t = proj[t] (same WG slice,
// same thread -> no hazard).  d_ws: 256 u32 flags (memset to 0 on stream).
// ============================================================================

#define T_STEPS 1024
#define HDIM    1024
#define EUL     0.01f

typedef unsigned long long u64_t;

// Coherent (L1+L2-bypassing) 16B load as 2x 8B system-scope relaxed atomics.
__device__ __forceinline__ float4 ldg_sys16(const float* p) {
  union { u64_t u; float f[2]; } a, b;
  a.u = __hip_atomic_load((u64_t*)p,       __ATOMIC_RELAXED,
                          __HIP_MEMORY_SCOPE_SYSTEM);
  b.u = __hip_atomic_load((u64_t*)(p + 2), __ATOMIC_RELAXED,
                          __HIP_MEMORY_SCOPE_SYSTEM);
  float4 r;
  r.x = a.f[0]; r.y = a.f[1]; r.z = b.f[0]; r.w = b.f[1];
  return r;
}

// ---------------------------------------------------------------------------
// Generic fp32 GEMM: C[M,N] = A[M,K] @ B[K,N], row-major, M%64==N%64==K%16==0
// 64x64 tile, 256 threads, 4x4 microtile.
// ---------------------------------------------------------------------------
__global__ __launch_bounds__(256) void gemm_f32(const float* __restrict__ A,
                                                const float* __restrict__ B,
                                                float* __restrict__ C,
                                                int M, int N, int K) {
  __shared__ float As[16][68];  // transposed: As[k][m], pad 68 for banks
  __shared__ float Bs[16][68];  // Bs[k][n]
  const int tid = threadIdx.x;
  const int tx = tid & 15;      // n/4
  const int ty = tid >> 4;      // m/4
  const int m0 = blockIdx.y * 64;
  const int n0 = blockIdx.x * 64;
  float acc[4][4] = {};

  for (int k0 = 0; k0 < K; k0 += 16) {
    // A tile 64x16: thread loads float4 at (m = tid>>2, k = (tid&3)*4)
    {
      const int m = tid >> 2;
      const int k = (tid & 3) * 4;
      const float4 a = *(const float4*)(A + (long)(m0 + m) * K + k0 + k);
      As[k + 0][m] = a.x; As[k + 1][m] = a.y;
      As[k + 2][m] = a.z; As[k + 3][m] = a.w;
      // B tile 16x64: thread loads float4 at (k = tid>>4, n = (tid&15)*4)
      const int kb = tid >> 4;
      const int n  = (tid & 15) * 4;
      *(float4*)&Bs[kb][n] = *(const float4*)(B + (long)(k0 + kb) * N + n0 + n);
    }
    __syncthreads();
#pragma unroll
    for (int k = 0; k < 16; ++k) {
      const float4 a = *(const float4*)&As[k][ty * 4];
      const float4 b = *(const float4*)&Bs[k][tx * 4];
      acc[0][0] += a.x * b.x; acc[0][1] += a.x * b.y; acc[0][2] += a.x * b.z; acc[0][3] += a.x * b.w;
      acc[1][0] += a.y * b.x; acc[1][1] += a.y * b.y; acc[1][2] += a.y * b.z; acc[1][3] += a.y * b.w;
      acc[2][0] += a.z * b.x; acc[2][1] += a.z * b.y; acc[2][2] += a.z * b.z; acc[2][3] += a.z * b.w;
      acc[3][0] += a.w * b.x; acc[3][1] += a.w * b.y; acc[3][2] += a.w * b.z; acc[3][3] += a.w * b.w;
    }
    __syncthreads();
  }
#pragma unroll
  for (int i = 0; i < 4; ++i) {
    float4 o;
    o.x = acc[i][0]; o.y = acc[i][1]; o.z = acc[i][2]; o.w = acc[i][3];
    *(float4*)(C + (long)(m0 + ty * 4 + i) * N + n0 + tx * 4) = o;
  }
}

// ---------------------------------------------------------------------------
// Persistent scan kernel.
// Grid: 256 WGs = 8 batch-groups (g = blockIdx&7, 8 batch rows) x 32 col
// slices (c = blockIdx>>3, 32 cols). 256 threads = 32 j-lanes x 8 k-splits.
// LDS: Clds[1024][32] = coupling + block_mat slice (fused; disjoint support)
//      hls [8][512]   = staged half of prev h (swizzled); aliased as redbuf
// Per-step sync: monotonic flags[w] = steps published.
// All cross-WG traffic (h stores, h loads, flags) is SYSTEM-scope relaxed
// (sc0 sc1 -> coherent at LLC). NO fences on the critical path.
// ---------------------------------------------------------------------------
__global__ __launch_bounds__(256) void scan_kernel(
    const float* __restrict__ block_mat,
    const float* __restrict__ coupling_mat,
    float* __restrict__ emb,          // [T][64][1024]; holds proj on entry
    unsigned int* __restrict__ flags) // [256], zeroed before launch
{
  __shared__ float Clds[1024 * 32];
  __shared__ float hls[8 * 512];

  const int tid = threadIdx.x;
  const int w = blockIdx.x;
  const int g = w & 7;           // batch group -> rows [8g, 8g+8)
  const int c = w >> 3;          // col slice   -> cols [32c, 32c+32)
  const int b0 = g * 8;
  const int cb = c * 32;
  const int bk = cb >> 6;        // 64-wide diag block index = c/2
  const int phase_blk = bk >> 3; // which 512-phase holds own-block rows
  const int j = tid & 31;        // column within slice
  const int s = tid >> 5;        // k-split 0..7
  const int jf = tid & 31;       // finalize mapping: col
  const int bf = tid >> 5;       // finalize mapping: batch row 0..7

  // ---- load fused weight slice: Clds[i][j] = coupling[i][cb+j] + block[i][cb+j]
  for (int q = 0; q < 32; ++q) {
    const int f = q * 1024 + tid * 4;  // flat float idx in 1024x32 tile
    const int i = f >> 5;
    const int jj = f & 31;
    const float4 cv = *(const float4*)(coupling_mat + (long)i * HDIM + cb + jj);
    const float4 bv = *(const float4*)(block_mat + (long)i * HDIM + cb + jj);
    float4 r;
    r.x = cv.x + bv.x; r.y = cv.y + bv.y; r.z = cv.z + bv.z; r.w = cv.w + bv.w;
    *(float4*)&Clds[f] = r;
  }
  __syncthreads();

  long spin_budget = 20000000;  // lifetime poll budget: hang-safety valve

  for (int t = 0; t < T_STEPS; ++t) {
    float acc[8];
#pragma unroll
    for (int b = 0; b < 8; ++b) acc[b] = 0.f;
    float h_old = 0.f;

    // u_t = proj[t] (still intact; only we overwrite it, at end of this step;
    // plain load is fine: written by the proj GEMM, coherent across the
    // kernel-dispatch boundary, and this line is only ever touched by us)
    const float u = emb[((long)t * 64 + b0 + bf) * HDIM + cb + jf];

    if (t > 0) {
      // ---- wait for the 32 producers of our batch group (incl. self)
      if (tid < 32) {
        const unsigned int tgt = (unsigned int)t;
        const int fl = (tid << 3) | g;
        while (__hip_atomic_load(&flags[fl], __ATOMIC_RELAXED,
                                 __HIP_MEMORY_SCOPE_SYSTEM) < tgt) {
          __builtin_amdgcn_s_sleep(2);
          if (--spin_budget < 0) break;
        }
      }
      __syncthreads();
      // no __threadfence(): staged loads below bypass L1/L2 (sc0 sc1) and
      // read the LLC, where the producers' sc1 stores already landed before
      // their flag was published.

      // ---- stage prev h [8][1024] in two 512-phases; all global loads first
      const int rr = tid >> 5;
      const int ccs = tid & 31;
      const float* srcp =
          emb + ((long)(t - 1) * 64 + b0 + rr) * HDIM + ccs * 16;
      float4 stg[8];
#pragma unroll
      for (int q = 0; q < 4; ++q) stg[q] = ldg_sys16(srcp + q * 4);
#pragma unroll
      for (int q = 0; q < 4; ++q) stg[4 + q] = ldg_sys16(srcp + 512 + q * 4);

#pragma unroll 1
      for (int p = 0; p < 2; ++p) {
        // write this phase into LDS (bank-swizzled at 16B granularity)
#pragma unroll
        for (int q = 0; q < 4; ++q) {
          const int io4 = ccs * 4 + q;
          const int sw = io4 ^ ((io4 >> 3) & 7);
          *(float4*)&hls[rr * 512 + sw * 4] = stg[p * 4 + q];
        }
        __syncthreads();

        // dense pass: acc[b] += sum_i h[b][i] * (C+B)[i][j]
        const int ibase = p * 512 + s * 64;
#pragma unroll 4
        for (int blk = 0; blk < 16; ++blk) {
          const int i = ibase + blk * 4;
          const int io4 = (i - p * 512) >> 2;
          const int sw = io4 ^ ((io4 >> 3) & 7);
          const float c0 = Clds[(i + 0) * 32 + j];
          const float c1 = Clds[(i + 1) * 32 + j];
          const float c2 = Clds[(i + 2) * 32 + j];
          const float c3 = Clds[(i + 3) * 32 + j];
#pragma unroll
          for (int b = 0; b < 8; ++b) {
            const float4 hv = *(const float4*)&hls[b * 512 + sw * 4];
            acc[b] += hv.x * c0 + hv.y * c1 + hv.z * c2 + hv.w * c3;
          }
        }

        if (phase_blk == p) {
          // correction on own-block rows: main loop used h*B there (C=0);
          // need relu(h)*B  ->  add (relu(h)-h)*B = -min(h,0)*B
          const int i0c = bk * 64 + s * 8;
#pragma unroll
          for (int blk2 = 0; blk2 < 2; ++blk2) {
            const int i = i0c + blk2 * 4;
            const int io4 = (i - p * 512) >> 2;
            const int sw = io4 ^ ((io4 >> 3) & 7);
            const float c0 = Clds[(i + 0) * 32 + j];
            const float c1 = Clds[(i + 1) * 32 + j];
            const float c2 = Clds[(i + 2) * 32 + j];
            const float c3 = Clds[(i + 3) * 32 + j];
#pragma unroll
            for (int b = 0; b < 8; ++b) {
              const float4 hv = *(const float4*)&hls[b * 512 + sw * 4];
              acc[b] -= fminf(hv.x, 0.f) * c0 + fminf(hv.y, 0.f) * c1 +
                        fminf(hv.z, 0.f) * c2 + fminf(hv.w, 0.f) * c3;
            }
          }
          // own h value (for the -h + ... update), finalize mapping
          const int io = (cb + jf) & 511;
          const int sw4 = (io >> 2) ^ (((io >> 2) >> 3) & 7);
          h_old = hls[bf * 512 + sw4 * 4 + (io & 3)];
        }
        __syncthreads();
      }
    }

    // ---- reduce 8 k-split partials: s-pair merge in-wave, then via LDS
#pragma unroll
    for (int b = 0; b < 8; ++b) acc[b] += __shfl_xor(acc[b], 32);
    const int wv = tid >> 6;  // wave id 0..3
    float* red = hls;         // alias: [4][32][12]
    __syncthreads();          // hls reads of this step are done
    if ((tid & 63) < 32) {
#pragma unroll
      for (int b = 0; b < 8; ++b) red[(wv * 32 + j) * 12 + b] = acc[b];
    }
    __syncthreads();
    float tot = 0.f;
#pragma unroll
    for (int q = 0; q < 4; ++q) tot += red[(q * 32 + jf) * 12 + bf];

    // ---- Euler update + publish (store bypasses L1/L2 -> visible at LLC)
    const float hn = h_old + EUL * (-h_old + tot + u);
    __hip_atomic_store(&emb[((long)t * 64 + b0 + bf) * HDIM + cb + jf], hn,
                       __ATOMIC_RELAXED, __HIP_MEMORY_SCOPE_SYSTEM);
    __syncthreads();  // barrier drains vmcnt: all WG h-stores complete at LLC
    if (tid == 0) {
      __hip_atomic_store(&flags[w], (unsigned int)(t + 1), __ATOMIC_RELAXED,
                         __HIP_MEMORY_SCOPE_SYSTEM);  // no wbl2: data is sc1
    }
  }
}

// ---------------------------------------------------------------------------
extern "C" void kernel_launch(void* const* d_in, const int* in_sizes, int n_in,
                              void* d_out, int out_size, void* d_ws,
                              size_t ws_size, hipStream_t stream) {
  (void)in_sizes; (void)n_in; (void)out_size; (void)ws_size;
  const float* input     = (const float*)d_in[0];  // [1024*64, 256]
  const float* input_mat = (const float*)d_in[1];  // [256, 1024]
  const float* block_mat = (const float*)d_in[2];  // [1024, 1024]
  const float* coupling  = (const float*)d_in[3];  // [1024, 1024]
  const float* out_mat   = (const float*)d_in[4];  // [1024, 256]

  float* out_ptr = (float*)d_out;                       // [65536, 256]
  float* emb_ptr = out_ptr + (size_t)1024 * 64 * 256;   // [65536, 1024]
  unsigned int* flags = (unsigned int*)d_ws;

  // 1) proj = input @ input_mat  -> embeddings region (consumed in-place)
  gemm_f32<<<dim3(1024 / 64, 65536 / 64), 256, 0, stream>>>(
      input, input_mat, emb_ptr, 65536, 1024, 256);

  // 2) zero the step flags
  hipMemsetAsync(flags, 0, 256 * sizeof(unsigned int), stream);

  // 3) persistent scan (256 WGs, exactly 1/CU by LDS footprint)
  scan_kernel<<<256, 256, 0, stream>>>(block_mat, coupling, emb_ptr, flags);

  // 4) output = embeddings @ out_mat
  gemm_f32<<<dim3(256 / 64, 65536 / 64), 256, 0, stream>>>(
      emb_ptr, out_mat, out_ptr, 65536, 256, 1024);
}

// Round 2
// 9997.417 us; speedup vs baseline: 3.4644x; 1.6486x over previous
//
#include <hip/hip_runtime.h>
#include <stdint.h>

// ============================================================================
// RNN2Layer: proj GEMM -> persistent Euler-scan kernel -> output GEMM
// All fp32. Round 2: the scan was LDS-issue-bound (≈400 LDS instr/thread/step
// at 4.5 B/FMA) plus serialized handoff. Changes:
//  - register tiling: thread = (j-quad, i-split of 32) -> 12 b128 reads per
//    128 FMAs (1.5 B/FMA), ~100 LDS instr/thread/step
//  - XOR slot-swizzle on the weight tile (bank-spread for strided b128 reads)
//  - 32-way k-split reduction via shfl_xor reduce-scatter (no LDS, no extra
//    barriers); each thread ends holding exactly its own (b, j) output
//  - per-thread producer polling (each thread waits only on the 2 flags
//    guarding the h-data it stages) + all staged loads issued up-front
// Cross-WG protocol unchanged from round 1: system-scope relaxed atomics
// (sc0 sc1, coherent at LLC), zero cache-maintenance on the critical path.
//
// Layout of d_out:  [0 .. 16777216)                 output     [1024][64][256]
//                   [16777216 .. 16777216+67108864) embeddings [1024][64][1024]
// emb initially holds proj (= input @ W_in); scan overwrites emb[t] with h_t
// after consuming u_t = proj[t] (same thread -> no hazard).
// d_ws: 256 u32 flags (memset 0 on stream).
// ============================================================================

#define T_STEPS 1024
#define HDIM    1024
#define EUL     0.01f

typedef unsigned long long u64_t;

// Coherent (L1+L2-bypassing) 16B load as 2x 8B system-scope relaxed atomics.
__device__ __forceinline__ float4 ldg_sys16(const float* p) {
  union { u64_t u; float f[2]; } a, b;
  a.u = __hip_atomic_load((const u64_t*)p,       __ATOMIC_RELAXED,
                          __HIP_MEMORY_SCOPE_SYSTEM);
  b.u = __hip_atomic_load((const u64_t*)(p + 2), __ATOMIC_RELAXED,
                          __HIP_MEMORY_SCOPE_SYSTEM);
  float4 r;
  r.x = a.f[0]; r.y = a.f[1]; r.z = b.f[0]; r.w = b.f[1];
  return r;
}

__device__ __forceinline__ void fma4(float4& a, float s, const float4& v) {
  a.x += s * v.x; a.y += s * v.y; a.z += s * v.z; a.w += s * v.w;
}

// ---------------------------------------------------------------------------
// Generic fp32 GEMM: C[M,N] = A[M,K] @ B[K,N], row-major, M%64==N%64==K%16==0
// 64x64 tile, 256 threads, 4x4 microtile.
// ---------------------------------------------------------------------------
__global__ __launch_bounds__(256) void gemm_f32(const float* __restrict__ A,
                                                const float* __restrict__ B,
                                                float* __restrict__ C,
                                                int M, int N, int K) {
  __shared__ float As[16][68];
  __shared__ float Bs[16][68];
  const int tid = threadIdx.x;
  const int tx = tid & 15;
  const int ty = tid >> 4;
  const int m0 = blockIdx.y * 64;
  const int n0 = blockIdx.x * 64;
  float acc[4][4] = {};

  for (int k0 = 0; k0 < K; k0 += 16) {
    {
      const int m = tid >> 2;
      const int k = (tid & 3) * 4;
      const float4 a = *(const float4*)(A + (long)(m0 + m) * K + k0 + k);
      As[k + 0][m] = a.x; As[k + 1][m] = a.y;
      As[k + 2][m] = a.z; As[k + 3][m] = a.w;
      const int kb = tid >> 4;
      const int n  = (tid & 15) * 4;
      *(float4*)&Bs[kb][n] = *(const float4*)(B + (long)(k0 + kb) * N + n0 + n);
    }
    __syncthreads();
#pragma unroll
    for (int k = 0; k < 16; ++k) {
      const float4 a = *(const float4*)&As[k][ty * 4];
      const float4 b = *(const float4*)&Bs[k][tx * 4];
      acc[0][0] += a.x * b.x; acc[0][1] += a.x * b.y; acc[0][2] += a.x * b.z; acc[0][3] += a.x * b.w;
      acc[1][0] += a.y * b.x; acc[1][1] += a.y * b.y; acc[1][2] += a.y * b.z; acc[1][3] += a.y * b.w;
      acc[2][0] += a.z * b.x; acc[2][1] += a.z * b.y; acc[2][2] += a.z * b.z; acc[2][3] += a.z * b.w;
      acc[3][0] += a.w * b.x; acc[3][1] += a.w * b.y; acc[3][2] += a.w * b.z; acc[3][3] += a.w * b.w;
    }
    __syncthreads();
  }
#pragma unroll
  for (int i = 0; i < 4; ++i) {
    float4 o;
    o.x = acc[i][0]; o.y = acc[i][1]; o.z = acc[i][2]; o.w = acc[i][3];
    *(float4*)(C + (long)(m0 + ty * 4 + i) * N + n0 + tx * 4) = o;
  }
}

// ---------------------------------------------------------------------------
// Persistent scan kernel.
// Grid: 256 WGs = 8 batch-groups (g = blockIdx&7, 8 rows) x 32 col slices
// (c = blockIdx>>3, 32 cols). Threads: qd = tid>>5 (j-quad 0..7, cols
// cb+qd*4..+4), s = tid&31 (i-split; per 512-phase covers 16 i-rows).
// LDS: Clds[1024][32] fused (coupling+block) weight slice, slot-swizzled:
//        row i stores j-quad `slot` at slot^((i>>5)&7)
//      hls [8][512]   staged phase of prev h, float4-swizzled (unchanged)
// Reduction: shfl_xor reduce-scatter over the 32 s-lanes; thread ends with
// its own output (b_f = s>>2, j_f = qd*4 + (s&3)).
// ---------------------------------------------------------------------------
__global__ __launch_bounds__(256) void scan_kernel(
    const float* __restrict__ block_mat,
    const float* __restrict__ coupling_mat,
    float* __restrict__ emb,          // [T][64][1024]; holds proj on entry
    unsigned int* __restrict__ flags) // [256], zeroed before launch
{
  __shared__ float Clds[1024 * 32];
  __shared__ float hls[8 * 512];

  const int tid = threadIdx.x;
  const int w = blockIdx.x;
  const int g = w & 7;            // batch group -> rows [8g, 8g+8)
  const int c = w >> 3;           // col slice   -> cols [32c, 32c+32)
  const int b0 = g * 8;
  const int cb = c * 32;
  const int bk = c >> 1;          // 64-wide diag block index
  const int phase_blk = bk >> 3;  // 512-phase containing own-block rows
  const int qd = tid >> 5;        // j-quad
  const int s  = tid & 31;        // i-split / staging col-chunk
  const int b_f = s >> 2;         // finalize: batch row 0..7
  const int j_f = (qd << 2) | (s & 3);  // finalize: col within slice
  const int pc  = s >> 1;         // producer slice (within phase) we stage

  // ---- fused weight slice, slot-swizzled:
  //      Clds[i*32 + ((slot^rot)<<2) + m] = C[i][cb+slot*4+m] + B[i][...]
  for (int q = 0; q < 32; ++q) {
    const int f = q * 1024 + tid * 4;  // flat idx in unswizzled 1024x32 tile
    const int i = f >> 5;
    const int slot = (f & 31) >> 2;
    const int rot = (i >> 5) & 7;
    const float4 cv = *(const float4*)(coupling_mat + (long)i * HDIM + cb + (slot << 2));
    const float4 bv = *(const float4*)(block_mat    + (long)i * HDIM + cb + (slot << 2));
    float4 r;
    r.x = cv.x + bv.x; r.y = cv.y + bv.y; r.z = cv.z + bv.z; r.w = cv.w + bv.w;
    *(float4*)&Clds[i * 32 + ((slot ^ rot) << 2)] = r;
  }
  __syncthreads();

  long spin_budget = 20000000;  // lifetime poll budget: hang-safety valve

  for (int t = 0; t < T_STEPS; ++t) {
    float4 accv[8];
#pragma unroll
    for (int b = 0; b < 8; ++b) { accv[b].x = 0.f; accv[b].y = 0.f; accv[b].z = 0.f; accv[b].w = 0.f; }
    float h_old = 0.f;

    // u_t = proj[t] for OUR output element (plain cached load; only we touch it)
    const float u = emb[((long)t * 64 + b0 + b_f) * HDIM + cb + j_f];

    if (t > 0) {
      // ---- per-thread wait: only the 2 producers guarding the 2 col-chunks
      //      THIS thread stages (c0 = pc for phase 0, c1 = 16+pc for phase 1)
      {
        const int fl0 = (pc << 3) | g;           // = producer WG id, phase 0
        const int fl1 = fl0 + 128;               // phase-1 producer (c+16)
        const unsigned int tgt = (unsigned int)t;
        while (true) {
          const unsigned int a = __hip_atomic_load(&flags[fl0], __ATOMIC_RELAXED,
                                                   __HIP_MEMORY_SCOPE_SYSTEM);
          const unsigned int b = __hip_atomic_load(&flags[fl1], __ATOMIC_RELAXED,
                                                   __HIP_MEMORY_SCOPE_SYSTEM);
          if (a >= tgt && b >= tgt) break;
          __builtin_amdgcn_s_sleep(2);
          if (--spin_budget < 0) break;
        }
        asm volatile("" ::: "memory");  // keep data loads after the poll
      }

      // ---- issue ALL staged loads up-front (both phases; 16B per phase-chunk)
      //      row = qd, cols = p*512 + s*16 .. +16 of prev h
      const float* srcp = emb + ((long)(t - 1) * 64 + b0 + qd) * HDIM + (s << 4);
      float4 stg[8];
#pragma unroll
      for (int q = 0; q < 4; ++q) stg[q]     = ldg_sys16(srcp + q * 4);
#pragma unroll
      for (int q = 0; q < 4; ++q) stg[4 + q] = ldg_sys16(srcp + 512 + q * 4);

#pragma unroll
      for (int p = 0; p < 2; ++p) {
        if (p) __syncthreads();  // phase-0 compute done before hls rewrite
        // write this phase into LDS (float4-granular swizzle, as before)
#pragma unroll
        for (int q = 0; q < 4; ++q) {
          const int io4 = (s << 2) | q;
          const int sw = io4 ^ ((io4 >> 3) & 7);
          *(float4*)&hls[qd * 512 + (sw << 2)] = stg[p * 4 + q];
        }
        __syncthreads();

        // ---- dense pass: 4 blocks of 4 i-rows; per block 12 b128 -> 128 FMA
#pragma unroll
        for (int blk = 0; blk < 4; ++blk) {
          const int i0 = (p << 9) + (s << 4) + (blk << 2);
          const int rot = (i0 >> 5) & 7;           // same for i0..i0+3
          const float* Cp = &Clds[i0 * 32 + ((qd ^ rot) << 2)];
          const float4 c0 = *(const float4*)(Cp + 0);
          const float4 c1 = *(const float4*)(Cp + 32);
          const float4 c2 = *(const float4*)(Cp + 64);
          const float4 c3 = *(const float4*)(Cp + 96);
          const int io4 = (s << 2) | blk;
          const int sw = io4 ^ ((io4 >> 3) & 7);
          const float* Hp = &hls[sw << 2];
#pragma unroll
          for (int b = 0; b < 8; ++b) {
            const float4 hv = *(const float4*)(Hp + b * 512);
            fma4(accv[b], hv.x, c0);
            fma4(accv[b], hv.y, c1);
            fma4(accv[b], hv.z, c2);
            fma4(accv[b], hv.w, c3);
          }
        }

        if (p == phase_blk) {
          // correction on own-block rows (coupling==0 there, Clds==B):
          // main loop used h*B; need relu(h)*B -> subtract min(h,0)*B.
          // 2 rows per thread: i0c, i0c+1 (all 256 threads participate).
          const int i0c = (bk << 6) | (s << 1);
          const int rotc = (i0c >> 5) & 7;
          const float* Cpc = &Clds[i0c * 32 + ((qd ^ rotc) << 2)];
          const float4 cA = *(const float4*)(Cpc + 0);
          const float4 cB = *(const float4*)(Cpc + 32);
          const int ioc = i0c & 511;
          const int io4c = ioc >> 2;
          const int swc = io4c ^ ((io4c >> 3) & 7);
          const int moc = ioc & 3;  // 0 or 2: aligned float2 within the quad
#pragma unroll
          for (int b = 0; b < 8; ++b) {
            const float2 hp = *(const float2*)&hls[b * 512 + (swc << 2) + moc];
            const float m0 = fminf(hp.x, 0.f);
            const float m1 = fminf(hp.y, 0.f);
            accv[b].x -= m0 * cA.x + m1 * cB.x;
            accv[b].y -= m0 * cA.y + m1 * cB.y;
            accv[b].z -= m0 * cA.z + m1 * cB.z;
            accv[b].w -= m0 * cA.w + m1 * cB.w;
          }
          // own h value (for -h + ... update)
          const int ioh = (cb + j_f) & 511;
          const int io4h = ioh >> 2;
          const int swh = io4h ^ ((io4h >> 3) & 7);
          h_old = hls[b_f * 512 + (swh << 2) + (ioh & 3)];
        }
      }
    }

    // ---- reduce-scatter the 32-way k-split over s-lanes (shfl only).
    // red[idx], idx = b*4+jj; after 5 rounds lane s holds idx == s fully
    // summed -> exactly this thread's output (b_f, j_f).
    float red[32];
#pragma unroll
    for (int b = 0; b < 8; ++b) {
      red[b * 4 + 0] = accv[b].x;
      red[b * 4 + 1] = accv[b].y;
      red[b * 4 + 2] = accv[b].z;
      red[b * 4 + 3] = accv[b].w;
    }
#define RED_ROUND(M)                                              \
    {                                                             \
      const bool hi = (tid & (M)) != 0;                           \
      _Pragma("unroll")                                           \
      for (int q = 0; q < (M); ++q) {                             \
        const float lo = red[q], hv2 = red[q + (M)];              \
        const float keep = hi ? hv2 : lo;                         \
        const float give = hi ? lo : hv2;                         \
        red[q] = keep + __shfl_xor(give, (M), 64);                \
      }                                                           \
    }
    RED_ROUND(16)
    RED_ROUND(8)
    RED_ROUND(4)
    RED_ROUND(2)
    RED_ROUND(1)
#undef RED_ROUND
    const float tot = red[0];

    // ---- Euler update + publish (store bypasses L1/L2 -> visible at LLC)
    const float hn = h_old + EUL * (-h_old + tot + u);
    __hip_atomic_store(&emb[((long)t * 64 + b0 + b_f) * HDIM + cb + j_f], hn,
                       __ATOMIC_RELAXED, __HIP_MEMORY_SCOPE_SYSTEM);
    __syncthreads();  // barrier drains vmcnt: all WG h-stores complete at LLC
                      // (also protects hls before next step's phase-0 write)
    if (tid == 0) {
      __hip_atomic_store(&flags[w], (unsigned int)(t + 1), __ATOMIC_RELAXED,
                         __HIP_MEMORY_SCOPE_SYSTEM);
    }
  }
}

// ---------------------------------------------------------------------------
extern "C" void kernel_launch(void* const* d_in, const int* in_sizes, int n_in,
                              void* d_out, int out_size, void* d_ws,
                              size_t ws_size, hipStream_t stream) {
  (void)in_sizes; (void)n_in; (void)out_size; (void)ws_size;
  const float* input     = (const float*)d_in[0];  // [1024*64, 256]
  const float* input_mat = (const float*)d_in[1];  // [256, 1024]
  const float* block_mat = (const float*)d_in[2];  // [1024, 1024]
  const float* coupling  = (const float*)d_in[3];  // [1024, 1024]
  const float* out_mat   = (const float*)d_in[4];  // [1024, 256]

  float* out_ptr = (float*)d_out;                       // [65536, 256]
  float* emb_ptr = out_ptr + (size_t)1024 * 64 * 256;   // [65536, 1024]
  unsigned int* flags = (unsigned int*)d_ws;

  // 1) proj = input @ input_mat  -> embeddings region (consumed in-place)
  gemm_f32<<<dim3(1024 / 64, 65536 / 64), 256, 0, stream>>>(
      input, input_mat, emb_ptr, 65536, 1024, 256);

  // 2) zero the step flags
  hipMemsetAsync(flags, 0, 256 * sizeof(unsigned int), stream);

  // 3) persistent scan (256 WGs, exactly 1/CU by LDS footprint)
  scan_kernel<<<256, 256, 0, stream>>>(block_mat, coupling, emb_ptr, flags);

  // 4) output = embeddings @ out_mat
  gemm_f32<<<dim3(256 / 64, 65536 / 64), 256, 0, stream>>>(
      emb_ptr, out_mat, out_ptr, 65536, 256, 1024);
}